// Round 3
// baseline (308.686 us; speedup 1.0000x reference)
//
#include <hip/hip_runtime.h>

// ws layout (float offsets)
#define LT0_OFF 0         // 16*50*64   = 51200
#define LT1_OFF 51200     // 16*100*112 = 179200
#define LT2_OFF 230400    // 16*150*160 = 384000
#define A0_OFF  614400    // 16*64*2  = 2048
#define A1_OFF  616448    // 16*112*2 = 3584
#define A2_OFF  620032    // 16*160*2 = 5120
#define PART_OFF 625152   // 48 partial ldj sums

__device__ __forceinline__ int tri_i(int p) { return (p * (p + 1)) >> 1; }

// Exact packed-triangle decode (e <= ~11k): 8e+1 fp32-exact, +-1 fixup.
__device__ __forceinline__ void tri_decode(int e, int& r, int& c) {
  r = (int)((sqrtf(8.0f * (float)e + 1.0f) - 1.0f) * 0.5f);
  if (tri_i(r + 1) <= e) ++r;
  if (tri_i(r) > e) --r;
  c = e - tri_i(r);
}

// fetch element of the register-resident 16x16 diag block (wave 0 only).
// idx = packed local index; slots ev0/ev1/ev2 hold indices [0,64),[64,128),[128,192)
#define DIAG_FETCH(idx, dst) {                                   \
    int _l = (idx) & 63, _sl = (idx) >> 6;                       \
    float _a = __shfl(ev[0], _l);                                \
    float _b = __shfl(ev[1], _l);                                \
    float _c = __shfl(ev[2], _l);                                \
    dst = (_sl == 0) ? _a : ((_sl == 1) ? _b : _c);              \
  }

// ---------------------------------------------------------------------------
// Kernel A: per (j,d) build A_mu, Sigma; blocked raw-Schur Cholesky (B=16):
//   phase 1: 16x16 diag factor, wave 0, registers + shfl (no LDS in chain)
//   phase 2: panel row-solve, 1 thread/row, registers, no barriers
//   phase 3: rank-16 trailing update, wave=2 rows, lane=col
// 3 barriers per panel (~30 total) instead of 2 per column (~300).
// ---------------------------------------------------------------------------
__global__ __launch_bounds__(1024) void build_kernel(const float* __restrict__ ts,
                                                     const float* __restrict__ log_tau,
                                                     float* __restrict__ ws)
{
  __shared__ float sS[11325];   // packed lower triangle, max m=150
  __shared__ float stj[152];
  __shared__ float sAmu[304];
  __shared__ float sKp[304];
  __shared__ float red[1024];

  const int j = blockIdx.x >> 4;
  const int d = blockIdx.x & 15;
  const int m = (j + 1) * 50;
  const int mp    = (j == 0) ? 64      : ((j == 1) ? 112     : 160);
  const int ltoff = (j == 0) ? LT0_OFF : ((j == 1) ? LT1_OFF : LT2_OFF);
  const int aoff  = (j == 0) ? A0_OFF  : ((j == 1) ? A1_OFF  : A2_OFF);
  const float tpsj = (j == 0) ? 10.0f : ((j == 1) ? 20.0f : 30.0f);
  const int tid  = threadIdx.x;
  const int lane = tid & 63;
  const int wid  = tid >> 6;        // 16 waves

  const float tau = expf(log_tau[d]);
  const float cc = 1.0f / (2.0f * tau * tau);

  for (int i = tid; i < m; i += 1024) stj[i] = ts[i];
  __syncthreads();

  const float k01 = expf(-tpsj * tpsj * cc);
  const float det = 1.0f - k01 * k01;
  const float i00 = 1.0f / det;
  const float i01 = -k01 / det;

  for (int p = tid; p < m; p += 1024) {
    float tp = stj[p];
    float kp0 = expf(-tp * tp * cc);
    float dt = tp - tpsj;
    float kp1 = expf(-dt * dt * cc);
    sKp[p * 2 + 0] = kp0; sKp[p * 2 + 1] = kp1;
    sAmu[p * 2 + 0] = fmaf(kp0, i00, kp1 * i01);
    sAmu[p * 2 + 1] = fmaf(kp0, i01, kp1 * i00);
  }
  __syncthreads();

  // Sigma (packed lower triangle)
  const int tot = tri_i(m);
  for (int e = tid; e < tot; e += 1024) {
    int r, q;
    tri_decode(e, r, q);
    float dq = stj[r] - stj[q];
    float v = expf(-dq * dq * cc)
            - fmaf(sAmu[r * 2], sKp[q * 2], sAmu[r * 2 + 1] * sKp[q * 2 + 1]);
    if (r == q) v += 1e-4f;
    sS[e] = v;
  }
  __syncthreads();

  // ---- Blocked raw-Schur Cholesky ----
  for (int kb = 0; kb < m - 1; kb += 16) {
    const int bw = (m - kb < 16) ? (m - kb) : 16;
    const int be = kb + bw;

    // phase 1: diag block factor (wave 0, registers + shfl)
    if (wid == 0) {
      const int tt = (bw * (bw + 1)) >> 1;
      int li[3], lq[3], ga[3];
      bool val[3];
      float ev[3];
#pragma unroll
      for (int s = 0; s < 3; ++s) {
        int e = lane + 64 * s;
        val[s] = (e < tt);
        int r = 0, c = 0;
        if (val[s]) tri_decode(e, r, c);
        li[s] = r; lq[s] = c;
        ga[s] = tri_i(kb + r) + kb + c;
        ev[s] = val[s] ? sS[ga[s]] : 0.0f;
      }
      for (int kk = 0; kk < bw - 1; ++kk) {
        float dkk;
        DIAG_FETCH(tri_i(kk) + kk, dkk);
        const float inv = -1.0f / dkk;
#pragma unroll
        for (int s = 0; s < 3; ++s) {
          float ci, cq;
          DIAG_FETCH(tri_i(li[s]) + kk, ci);
          DIAG_FETCH(tri_i(lq[s]) + kk, cq);
          if (val[s] && lq[s] > kk)
            ev[s] = fmaf(ci * inv, cq, ev[s]);
        }
      }
#pragma unroll
      for (int s = 0; s < 3; ++s) if (val[s]) sS[ga[s]] = ev[s];
    }
    __syncthreads();

    if (be < m) {
      // per-thread inv_d of the panel diag (broadcast reads)
      float invd[16];
#pragma unroll
      for (int t = 0; t < 16; ++t)
        invd[t] = (t < bw) ? (1.0f / sS[tri_i(kb + t) + kb + t]) : 0.0f;

      // phase 2: panel row-solve, one thread per row i in [be, m)
      {
        const int i = be + tid;
        if (i < m) {
          const int base = tri_i(i) + kb;
          float r[16];
#pragma unroll
          for (int t = 0; t < 16; ++t) r[t] = (t < bw) ? sS[base + t] : 0.0f;
#pragma unroll
          for (int kk = 0; kk < 15; ++kk) {
            if (kk < bw - 1) {
              const float c = r[kk] * invd[kk];
#pragma unroll
              for (int q = kk + 1; q < 16; ++q) {
                if (q < bw)
                  r[q] = fmaf(-c, sS[tri_i(kb + q) + kb + kk], r[q]);
              }
            }
          }
#pragma unroll
          for (int t = 0; t < 16; ++t) if (t < bw) sS[base + t] = r[t];
        }
      }
      __syncthreads();

      // phase 3: rank-16 trailing update. wave = 2-row group, lane = col.
      {
        const int ntrail = m - be;
        const int ngroups = (ntrail + 1) >> 1;
        for (int g = wid; g < ngroups; g += 16) {
          const int i0 = be + g * 2;
          const int i1 = i0 + 1;
          // W rows (scaled), broadcast reads
          float w0[16], w1[16];
          {
            const int rb0 = tri_i(i0) + kb;
            const int rb1 = tri_i((i1 < m) ? i1 : i0) + kb;
#pragma unroll
            for (int t = 0; t < 16; ++t) {
              w0[t] = (t < bw) ? sS[rb0 + t] * invd[t] : 0.0f;
              w1[t] = (t < bw && i1 < m) ? sS[rb1 + t] * invd[t] : 0.0f;
            }
          }
          const int qmax = (i1 < m) ? i1 : i0;
          for (int q = be + lane; q <= qmax; q += 64) {
            const int qb = tri_i(q) + kb;
            float u[16];
#pragma unroll
            for (int t = 0; t < 16; ++t) u[t] = (t < bw) ? sS[qb + t] : 0.0f;
            if (q <= i0) {
              const int a = tri_i(i0) + q;
              float acc = sS[a];
#pragma unroll
              for (int t = 0; t < 16; ++t) acc = fmaf(-w0[t], u[t], acc);
              sS[a] = acc;
            }
            if (i1 < m && q <= i1) {
              const int a = tri_i(i1) + q;
              float acc = sS[a];
#pragma unroll
              for (int t = 0; t < 16; ++t) acc = fmaf(-w1[t], u[t], acc);
              sS[a] = acc;
            }
          }
        }
      }
      __syncthreads();
    }
  }

  // ldj partial: sum 0.5*log(d_p)
  float part = 0.0f;
  for (int p = tid; p < m; p += 1024) part += 0.5f * logf(sS[tri_i(p) + p]);
  red[tid] = part;
  __syncthreads();
  for (int s = 512; s > 0; s >>= 1) {
    if (tid < s) red[tid] += red[tid + s];
    __syncthreads();
  }
  if (tid == 0) ws[PART_OFF + blockIdx.x] = red[0];

  // L^T write, zero-padded
  float* LTg = ws + ltoff + d * (m * mp);
  for (int idx = tid; idx < m * mp; idx += 1024) {
    int q = idx / mp;
    int p = idx - q * mp;
    float v = 0.0f;
    if (p < m && p >= q) {
      float dq = sS[tri_i(q) + q];
      v = (p == q) ? sqrtf(dq) : sS[tri_i(p) + q] * rsqrtf(dq);
    }
    LTg[idx] = v;
  }
  float* Ag = ws + aoff + d * (mp * 2);
  for (int idx = tid; idx < mp * 2; idx += 1024) {
    int p = idx >> 1;
    Ag[idx] = (p < m) ? sAmu[idx] : 0.0f;
  }
}

// ---------------------------------------------------------------------------
// Kernel B: z_hat = A_mu * z_EP + L * z_mid. 512 threads (8 waves), lane=row,
// wave owns p-groups of 16, L rows via float4 loads, q unrolled x2.
// ---------------------------------------------------------------------------
#define TPB 512

template <int M, int MP, int TOFF, int OOFF, int LTOFF, int AOFF>
__device__ __forceinline__ void apply_impl(const float* __restrict__ z,
                                           const float* __restrict__ ws,
                                           float* __restrict__ out,
                                           float* zsh, int blk)
{
  constexpr int W = M + 3;            // odd row stride -> conflict-free columns
  constexpr int G = MP / 16;          // p-groups
  constexpr int NGW = (G + 7) / 8;    // groups per wave
  const int d = blk & 15;
  const int bs0 = (blk >> 4) * 64;
  const int tid = threadIdx.x;
  const int lane = tid & 63;
  const int w = __builtin_amdgcn_readfirstlane(tid >> 6);

  // stage rows: [zf, zl, z_mid(0..M-1)]
  const float* zbase = z + (size_t)(bs0 * 16 + d) * 302;
  for (int idx = tid; idx < 64 * (M + 2); idx += TPB) {
    int rr = idx / (M + 2);
    int c = idx - rr * (M + 2);
    int t = (c < 2) ? c : (TOFF + c - 2);
    zsh[rr * W + c] = zbase[(size_t)rr * 4832 + t];
  }
  __syncthreads();

  float acc[NGW][16];
  const float* Ad = ws + AOFF + d * (MP * 2);
  const float* Ld = ws + LTOFF + d * (M * MP);
  const float zf = zsh[lane * W + 0];
  const float zl = zsh[lane * W + 1];

#pragma unroll
  for (int gi = 0; gi < NGW; ++gi) {
    const int g = w + 8 * gi;
    if (g < G) {
      const int pbase = g * 16;
#pragma unroll
      for (int i = 0; i < 16; ++i)
        acc[gi][i] = fmaf(Ad[(pbase + i) * 2 + 0], zf, Ad[(pbase + i) * 2 + 1] * zl);
      const float* Lp = Ld + pbase;
      for (int q = 0; q < M; q += 2) {
        const float4* a4 = (const float4*)(Lp + (size_t)q * MP);
        const float4* b4 = (const float4*)(Lp + (size_t)(q + 1) * MP);
        float la[16], lb[16];
        *(float4*)&la[0]  = a4[0]; *(float4*)&la[4]  = a4[1];
        *(float4*)&la[8]  = a4[2]; *(float4*)&la[12] = a4[3];
        *(float4*)&lb[0]  = b4[0]; *(float4*)&lb[4]  = b4[1];
        *(float4*)&lb[8]  = b4[2]; *(float4*)&lb[12] = b4[3];
        const float zv0 = zsh[lane * W + 2 + q];
        const float zv1 = zsh[lane * W + 3 + q];
#pragma unroll
        for (int i = 0; i < 16; ++i)
          acc[gi][i] = fmaf(la[i], zv0, acc[gi][i]);
#pragma unroll
        for (int i = 0; i < 16; ++i)
          acc[gi][i] = fmaf(lb[i], zv1, acc[gi][i]);
      }
    }
  }
  __syncthreads();

  // write z_hat back into the LDS tile (cols 2..M+1)
#pragma unroll
  for (int gi = 0; gi < NGW; ++gi) {
    const int g = w + 8 * gi;
    if (g < G) {
      const int pbase = g * 16;
#pragma unroll
      for (int i = 0; i < 16; ++i) {
        const int p = pbase + i;
        if (p < M) zsh[lane * W + 2 + p] = acc[gi][i];
      }
    }
  }
  __syncthreads();

  // coalesced store: out row segment = [zf, z_hat(0..M-1), zl]
  for (int idx = tid; idx < 64 * (M + 2); idx += TPB) {
    int rr = idx / (M + 2);
    int c = idx - rr * (M + 2);
    float v = (c == 0) ? zsh[rr * W]
            : ((c == M + 1) ? zsh[rr * W + 1] : zsh[rr * W + c + 1]);
    out[(size_t)((bs0 + rr) * 16 + d) * 306 + OOFF + c] = v;
  }
}

__global__ __launch_bounds__(TPB) void apply_kernel(const float* __restrict__ z,
                                                    const float* __restrict__ ws,
                                                    float* __restrict__ out)
{
  __shared__ float zsh[64 * 153];
  const int bid = blockIdx.x;
  if (bid < 512)       apply_impl<150, 160, 152, 154, LT2_OFF, A2_OFF>(z, ws, out, zsh, bid);
  else if (bid < 1024) apply_impl<100, 112,  52,  52, LT1_OFF, A1_OFF>(z, ws, out, zsh, bid - 512);
  else                 apply_impl< 50,  64,   2,   0, LT0_OFF, A0_OFF>(z, ws, out, zsh, bid - 1024);
}

// ---------------------------------------------------------------------------
// Kernel C: ldj = sldj_in + sum of 48 partials
// ---------------------------------------------------------------------------
__global__ void finalize_kernel(const float* __restrict__ ws_part,
                                const float* __restrict__ sldj,
                                float* __restrict__ out, int last)
{
  if (threadIdx.x == 0) {
    float s = sldj[0];
    for (int i = 0; i < 48; ++i) s += ws_part[i];
    out[last] = s;
  }
}

extern "C" void kernel_launch(void* const* d_in, const int* in_sizes, int n_in,
                              void* d_out, int out_size, void* d_ws, size_t ws_size,
                              hipStream_t stream)
{
  const float* z       = (const float*)d_in[0];  // (16,128,16,302)
  const float* ts      = (const float*)d_in[1];  // (3,50) flat
  const float* log_tau = (const float*)d_in[2];  // (16,)
  const float* sldj    = (const float*)d_in[3];  // scalar
  float* out = (float*)d_out;                    // 16*128*16*306 + 1
  float* ws  = (float*)d_ws;

  hipLaunchKernelGGL(build_kernel, dim3(48), dim3(1024), 0, stream, ts, log_tau, ws);
  hipLaunchKernelGGL(apply_kernel, dim3(1536), dim3(TPB), 0, stream, z, ws, out);
  hipLaunchKernelGGL(finalize_kernel, dim3(1), dim3(64), 0, stream,
                     ws + PART_OFF, sldj, out, out_size - 1);
}

// Round 4
// 302.117 us; speedup vs baseline: 1.0217x; 1.0217x over previous
//
#include <hip/hip_runtime.h>

// ws layout (float offsets)
#define LT0_OFF 0         // 16*50*64   = 51200
#define LT1_OFF 51200     // 16*100*112 = 179200
#define LT2_OFF 230400    // 16*150*160 = 384000
#define A0_OFF  614400    // 16*64*2  = 2048
#define A1_OFF  616448    // 16*112*2 = 3584
#define A2_OFF  620032    // 16*160*2 = 5120
#define PART_OFF 625152   // 48 partial ldj sums

__device__ __forceinline__ int tri_i(int p) { return (p * (p + 1)) >> 1; }

// Exact packed-triangle decode (e <= ~13k): 8e+1 fp32-exact, +-1 fixup.
__device__ __forceinline__ void tri_decode(int e, int& r, int& c) {
  r = (int)((sqrtf(8.0f * (float)e + 1.0f) - 1.0f) * 0.5f);
  if (tri_i(r + 1) <= e) ++r;
  if (tri_i(r) > e) --r;
  c = e - tri_i(r);
}

// ---------------------------------------------------------------------------
// Kernel A: per (j,d): Sigma (padded to mp with identity tail -> bw==16
// always, every loop compile-time), blocked raw-Schur Cholesky B=16:
//   phase A: 16x16 diag factor, lanes 0..15 of wave 0, rows in REGISTERS,
//            cross-lane via __shfl with compile-time lane index (no LDS chain)
//   phase B: panel row-solve, 1 thread/row, registers, broadcast diag reads
//   phase C: rank-16 trailing update, wave = row pair, lane = column chunk
// ---------------------------------------------------------------------------
__global__ __launch_bounds__(1024) void build_kernel(const float* __restrict__ ts,
                                                     const float* __restrict__ log_tau,
                                                     float* __restrict__ ws)
{
  __shared__ float sS[12880];   // packed lower triangle, padded max mp=160
  __shared__ float stj[152];
  __shared__ float sAmu[304];
  __shared__ float sKp[304];
  __shared__ float red[1024];

  const int j = blockIdx.x >> 4;
  const int d = blockIdx.x & 15;
  const int m = (j + 1) * 50;
  const int mp    = (j == 0) ? 64      : ((j == 1) ? 112     : 160);
  const int ltoff = (j == 0) ? LT0_OFF : ((j == 1) ? LT1_OFF : LT2_OFF);
  const int aoff  = (j == 0) ? A0_OFF  : ((j == 1) ? A1_OFF  : A2_OFF);
  const float tpsj = (j == 0) ? 10.0f : ((j == 1) ? 20.0f : 30.0f);
  const int tid  = threadIdx.x;
  const int lane = tid & 63;
  const int wid  = tid >> 6;        // 16 waves

  const float tau = expf(log_tau[d]);
  const float cc = 1.0f / (2.0f * tau * tau);

  for (int i = tid; i < m; i += 1024) stj[i] = ts[i];
  __syncthreads();

  const float k01 = expf(-tpsj * tpsj * cc);
  const float det = 1.0f - k01 * k01;
  const float i00 = 1.0f / det;
  const float i01 = -k01 / det;

  for (int p = tid; p < m; p += 1024) {
    float tp = stj[p];
    float kp0 = expf(-tp * tp * cc);
    float dt = tp - tpsj;
    float kp1 = expf(-dt * dt * cc);
    sKp[p * 2 + 0] = kp0; sKp[p * 2 + 1] = kp1;
    sAmu[p * 2 + 0] = fmaf(kp0, i00, kp1 * i01);
    sAmu[p * 2 + 1] = fmaf(kp0, i01, kp1 * i00);
  }
  __syncthreads();

  // Sigma, padded: rows >= m are identity (d=1, off-diag 0) -> log contrib 0.
  const int tot = tri_i(mp);
  for (int e = tid; e < tot; e += 1024) {
    int r, q;
    tri_decode(e, r, q);
    float v;
    if (r < m) {
      float dq = stj[r] - stj[q];
      v = expf(-dq * dq * cc)
        - fmaf(sAmu[r * 2], sKp[q * 2], sAmu[r * 2 + 1] * sKp[q * 2 + 1]);
      if (r == q) v += 1e-4f;
    } else {
      v = (r == q) ? 1.0f : 0.0f;
    }
    sS[e] = v;
  }
  __syncthreads();

  // ---- Blocked raw-Schur Cholesky, bw == 16 always ----
  const int npan = mp >> 4;
  for (int pb = 0; pb < npan; ++pb) {
    const int kb = pb << 4;
    const int be = kb + 16;

    // phase A: diag block factor. lane t (t<16) = row t in registers.
    if (wid == 0) {
      const int tr = lane & 15;                 // clamp for lanes >= 16
      const int rbase = tri_i(kb + tr) + kb;
      float r[16];
#pragma unroll
      for (int q = 0; q < 16; ++q) r[q] = sS[rbase + q];
#pragma unroll
      for (int kk = 0; kk < 15; ++kk) {
        const float dkk = __shfl(r[kk], kk);
        const float c = r[kk] * (-1.0f / dkk);  // lane's own col-kk value
#pragma unroll
        for (int q2 = kk + 1; q2 < 16; ++q2) {
          const float cq2 = __shfl(r[kk], q2);  // compile-time lane index
          if (tr > kk && q2 <= tr)
            r[q2] = fmaf(c, cq2, r[q2]);
        }
      }
      if (lane < 16) {
#pragma unroll
        for (int q = 0; q < 16; ++q) if (q <= tr) sS[rbase + q] = r[q];
      }
    }
    __syncthreads();

    if (be < mp) {
      float invd[16];
#pragma unroll
      for (int t = 0; t < 16; ++t)
        invd[t] = 1.0f / sS[tri_i(kb + t) + kb + t];

      // phase B: row-solve, one thread per row i in [be, mp)
      {
        const int i = be + tid;
        if (i < mp) {
          const int base = tri_i(i) + kb;
          float r[16];
#pragma unroll
          for (int t = 0; t < 16; ++t) r[t] = sS[base + t];
#pragma unroll
          for (int kk = 0; kk < 15; ++kk) {
            const float c = r[kk] * invd[kk];
#pragma unroll
            for (int q = kk + 1; q < 16; ++q)
              r[q] = fmaf(-c, sS[tri_i(kb + q) + kb + kk], r[q]);
          }
#pragma unroll
          for (int t = 0; t < 16; ++t) sS[base + t] = r[t];
        }
      }
      __syncthreads();

      // phase C: trailing update. wave = row pair, lane = column chunk.
      for (int i0 = be + 2 * wid; i0 < mp; i0 += 32) {
        const int i1 = i0 + 1;
        const int rb0 = tri_i(i0) + kb;
        const int rb1 = tri_i(i1) + kb;
        float w0[16], w1[16];
#pragma unroll
        for (int t = 0; t < 16; ++t) {
          w0[t] = sS[rb0 + t] * invd[t];
          w1[t] = sS[rb1 + t] * invd[t];
        }
        const int b0 = tri_i(i0);
        const int b1 = tri_i(i1);
        for (int q0 = be; q0 <= i1; q0 += 64) {
          const int q = q0 + lane;
          const int qc = (q <= i1) ? q : i1;     // clamp address in-bounds
          const int qb = tri_i(qc) + kb;
          float u[16];
#pragma unroll
          for (int t = 0; t < 16; ++t) u[t] = sS[qb + t];
          if (q <= i0) {
            float a = sS[b0 + q];
#pragma unroll
            for (int t = 0; t < 16; ++t) a = fmaf(-w0[t], u[t], a);
            sS[b0 + q] = a;
          }
          if (q <= i1) {
            float a = sS[b1 + q];
#pragma unroll
            for (int t = 0; t < 16; ++t) a = fmaf(-w1[t], u[t], a);
            sS[b1 + q] = a;
          }
        }
      }
      __syncthreads();
    }
  }

  // ldj partial: sum 0.5*log(d_p) over real rows
  float part = 0.0f;
  for (int p = tid; p < m; p += 1024) part += 0.5f * logf(sS[tri_i(p) + p]);
  red[tid] = part;
  __syncthreads();
  for (int s = 512; s > 0; s >>= 1) {
    if (tid < s) red[tid] += red[tid + s];
    __syncthreads();
  }
  if (tid == 0) ws[PART_OFF + blockIdx.x] = red[0];

  // L^T write, zero-padded: LT[q][p] = L[p][q]
  float* LTg = ws + ltoff + d * (m * mp);
  for (int idx = tid; idx < m * mp; idx += 1024) {
    int q = idx / mp;
    int p = idx - q * mp;
    float v = 0.0f;
    if (p < m && p >= q) {
      float dq = sS[tri_i(q) + q];
      v = (p == q) ? sqrtf(dq) : sS[tri_i(p) + q] * rsqrtf(dq);
    }
    LTg[idx] = v;
  }
  float* Ag = ws + aoff + d * (mp * 2);
  for (int idx = tid; idx < mp * 2; idx += 1024) {
    int p = idx >> 1;
    Ag[idx] = (p < m) ? sAmu[idx] : 0.0f;
  }
}

// ---------------------------------------------------------------------------
// Kernel B: z_hat = A_mu * z_EP + L * z_mid. 512 threads (8 waves), lane=row.
// Wave w owns contiguous p-chunk [w*PC, (w+1)*PC), PC = MP/8 -> perfectly
// balanced. L rows wave-uniform (scalar loads), q unrolled x2.
// ---------------------------------------------------------------------------
#define TPB 512

template <int M, int MP, int PC, int TOFF, int OOFF, int LTOFF, int AOFF>
__device__ __forceinline__ void apply_impl(const float* __restrict__ z,
                                           const float* __restrict__ ws,
                                           float* __restrict__ out,
                                           float* zsh, int blk)
{
  constexpr int W = M + 3;            // odd row stride -> conflict-free columns
  const int d = blk & 15;
  const int bs0 = (blk >> 4) * 64;
  const int tid = threadIdx.x;
  const int lane = tid & 63;
  const int w = __builtin_amdgcn_readfirstlane(tid >> 6);
  const int p0 = w * PC;

  // stage rows: [zf, zl, z_mid(0..M-1)]
  const float* zbase = z + (size_t)(bs0 * 16 + d) * 302;
  for (int idx = tid; idx < 64 * (M + 2); idx += TPB) {
    int rr = idx / (M + 2);
    int c = idx - rr * (M + 2);
    int t = (c < 2) ? c : (TOFF + c - 2);
    zsh[rr * W + c] = zbase[(size_t)rr * 4832 + t];
  }
  __syncthreads();

  float acc[PC];
  const float* Ad = ws + AOFF + d * (MP * 2) + p0 * 2;
  const float* Ld = ws + LTOFF + d * (M * MP) + p0;
  const float zf = zsh[lane * W + 0];
  const float zl = zsh[lane * W + 1];

#pragma unroll
  for (int i = 0; i < PC; ++i)
    acc[i] = fmaf(Ad[i * 2 + 0], zf, Ad[i * 2 + 1] * zl);

  for (int q = 0; q < M; q += 2) {
    const float* La = Ld + (size_t)q * MP;
    const float* Lb = Ld + (size_t)(q + 1) * MP;
    float la[PC], lb[PC];
#pragma unroll
    for (int i = 0; i < PC; ++i) { la[i] = La[i]; lb[i] = Lb[i]; }
    const float zv0 = zsh[lane * W + 2 + q];
    const float zv1 = zsh[lane * W + 3 + q];
#pragma unroll
    for (int i = 0; i < PC; ++i) acc[i] = fmaf(la[i], zv0, acc[i]);
#pragma unroll
    for (int i = 0; i < PC; ++i) acc[i] = fmaf(lb[i], zv1, acc[i]);
  }
  __syncthreads();

  // write z_hat back into the LDS tile (cols 2..M+1)
#pragma unroll
  for (int i = 0; i < PC; ++i) {
    const int p = p0 + i;
    if (p < M) zsh[lane * W + 2 + p] = acc[i];
  }
  __syncthreads();

  // coalesced store: out row segment = [zf, z_hat(0..M-1), zl]
  for (int idx = tid; idx < 64 * (M + 2); idx += TPB) {
    int rr = idx / (M + 2);
    int c = idx - rr * (M + 2);
    float v = (c == 0) ? zsh[rr * W]
            : ((c == M + 1) ? zsh[rr * W + 1] : zsh[rr * W + c + 1]);
    out[(size_t)((bs0 + rr) * 16 + d) * 306 + OOFF + c] = v;
  }
}

__global__ __launch_bounds__(TPB) void apply_kernel(const float* __restrict__ z,
                                                    const float* __restrict__ ws,
                                                    float* __restrict__ out)
{
  __shared__ float zsh[64 * 153];
  const int bid = blockIdx.x;
  if (bid < 512)       apply_impl<150, 160, 20, 152, 154, LT2_OFF, A2_OFF>(z, ws, out, zsh, bid);
  else if (bid < 1024) apply_impl<100, 112, 14,  52,  52, LT1_OFF, A1_OFF>(z, ws, out, zsh, bid - 512);
  else                 apply_impl< 50,  64,  8,   2,   0, LT0_OFF, A0_OFF>(z, ws, out, zsh, bid - 1024);
}

// ---------------------------------------------------------------------------
// Kernel C: ldj = sldj_in + sum of 48 partials
// ---------------------------------------------------------------------------
__global__ void finalize_kernel(const float* __restrict__ ws_part,
                                const float* __restrict__ sldj,
                                float* __restrict__ out, int last)
{
  if (threadIdx.x == 0) {
    float s = sldj[0];
    for (int i = 0; i < 48; ++i) s += ws_part[i];
    out[last] = s;
  }
}

extern "C" void kernel_launch(void* const* d_in, const int* in_sizes, int n_in,
                              void* d_out, int out_size, void* d_ws, size_t ws_size,
                              hipStream_t stream)
{
  const float* z       = (const float*)d_in[0];  // (16,128,16,302)
  const float* ts      = (const float*)d_in[1];  // (3,50) flat
  const float* log_tau = (const float*)d_in[2];  // (16,)
  const float* sldj    = (const float*)d_in[3];  // scalar
  float* out = (float*)d_out;                    // 16*128*16*306 + 1
  float* ws  = (float*)d_ws;

  hipLaunchKernelGGL(build_kernel, dim3(48), dim3(1024), 0, stream, ts, log_tau, ws);
  hipLaunchKernelGGL(apply_kernel, dim3(1536), dim3(TPB), 0, stream, z, ws, out);
  hipLaunchKernelGGL(finalize_kernel, dim3(1), dim3(64), 0, stream,
                     ws + PART_OFF, sldj, out, out_size - 1);
}

// Round 5
// 206.568 us; speedup vs baseline: 1.4944x; 1.4626x over previous
//
#include <hip/hip_runtime.h>

// ws layout (32-bit word offsets). LB arrays are bf16-packed (2 per word):
// LB[j][d] has MP rows, KS bf16 columns (row stride KS), row p holds
// [ L[p][0..M-1], A_mu[p][0], A_mu[p][1], zeros... ]
#define LB0_OFF 0         // 16 * (64*72/2)   = 16*2304  = 36864
#define LB1_OFF 36864     // 16 * (112*136/2) = 16*7616  = 121856
#define LB2_OFF 158720    // 16 * (160*168/2) = 16*13440 = 215040
#define PART_OFF 373760   // 48 partial ldj sums (float)

typedef __attribute__((ext_vector_type(8))) short bf8_t;    // 8 bf16 (4 VGPR)
typedef __attribute__((ext_vector_type(8))) unsigned short us8_t;
typedef __attribute__((ext_vector_type(4))) float f32x4;

__device__ __forceinline__ int tri_i(int p) { return (p * (p + 1)) >> 1; }

__device__ __forceinline__ void tri_decode(int e, int& r, int& c) {
  r = (int)((sqrtf(8.0f * (float)e + 1.0f) - 1.0f) * 0.5f);
  if (tri_i(r + 1) <= e) ++r;
  if (tri_i(r) > e) --r;
  c = e - tri_i(r);
}

// fp32 -> bf16, round-nearest-even
__device__ __forceinline__ unsigned short f2bf(float f) {
  unsigned u = __builtin_bit_cast(unsigned, f);
  u = (u + 0x7FFFu + ((u >> 16) & 1u)) >> 16;
  return (unsigned short)u;
}

// ---------------------------------------------------------------------------
// Kernel A: per (j,d) Sigma (padded to MP, identity tail), blocked raw-Schur
// Cholesky (B=16), then emit LB (bf16) = [L | A_mu cols | 0] and ldj partial.
// ---------------------------------------------------------------------------
__global__ __launch_bounds__(1024) void build_kernel(const float* __restrict__ ts,
                                                     const float* __restrict__ log_tau,
                                                     float* __restrict__ ws)
{
  __shared__ float sS[12880];   // packed lower triangle, padded max mp=160
  __shared__ float stj[152];
  __shared__ float sAmu[304];
  __shared__ float sKp[304];
  __shared__ float red[1024];

  const int j = blockIdx.x >> 4;
  const int d = blockIdx.x & 15;
  const int m = (j + 1) * 50;
  const int mp    = (j == 0) ? 64      : ((j == 1) ? 112     : 160);
  const int ks    = (j == 0) ? 72      : ((j == 1) ? 136     : 168);
  const int lboff = (j == 0) ? LB0_OFF : ((j == 1) ? LB1_OFF : LB2_OFF);
  const float tpsj = (j == 0) ? 10.0f : ((j == 1) ? 20.0f : 30.0f);
  const int tid  = threadIdx.x;
  const int lane = tid & 63;
  const int wid  = tid >> 6;        // 16 waves

  const float tau = expf(log_tau[d]);
  const float cc = 1.0f / (2.0f * tau * tau);

  for (int i = tid; i < m; i += 1024) stj[i] = ts[i];
  __syncthreads();

  const float k01 = expf(-tpsj * tpsj * cc);
  const float det = 1.0f - k01 * k01;
  const float i00 = 1.0f / det;
  const float i01 = -k01 / det;

  for (int p = tid; p < m; p += 1024) {
    float tp = stj[p];
    float kp0 = expf(-tp * tp * cc);
    float dt = tp - tpsj;
    float kp1 = expf(-dt * dt * cc);
    sKp[p * 2 + 0] = kp0; sKp[p * 2 + 1] = kp1;
    sAmu[p * 2 + 0] = fmaf(kp0, i00, kp1 * i01);
    sAmu[p * 2 + 1] = fmaf(kp0, i01, kp1 * i00);
  }
  __syncthreads();

  // Sigma, padded: rows >= m are identity -> log contrib 0, L tail ignored.
  const int tot = tri_i(mp);
  for (int e = tid; e < tot; e += 1024) {
    int r, q;
    tri_decode(e, r, q);
    float v;
    if (r < m) {
      float dq = stj[r] - stj[q];
      v = expf(-dq * dq * cc)
        - fmaf(sAmu[r * 2], sKp[q * 2], sAmu[r * 2 + 1] * sKp[q * 2 + 1]);
      if (r == q) v += 1e-4f;
    } else {
      v = (r == q) ? 1.0f : 0.0f;
    }
    sS[e] = v;
  }
  __syncthreads();

  // ---- Blocked raw-Schur Cholesky, bw == 16 always ----
  const int npan = mp >> 4;
  for (int pb = 0; pb < npan; ++pb) {
    const int kb = pb << 4;
    const int be = kb + 16;

    // phase A: diag block factor. lane t (t<16) = row t in registers.
    if (wid == 0) {
      const int tr = lane & 15;
      const int rbase = tri_i(kb + tr) + kb;
      float r[16];
#pragma unroll
      for (int q = 0; q < 16; ++q) r[q] = sS[rbase + q];
#pragma unroll
      for (int kk = 0; kk < 15; ++kk) {
        const float dkk = __shfl(r[kk], kk);
        const float c = r[kk] * (-1.0f / dkk);
#pragma unroll
        for (int q2 = kk + 1; q2 < 16; ++q2) {
          const float cq2 = __shfl(r[kk], q2);
          if (tr > kk && q2 <= tr)
            r[q2] = fmaf(c, cq2, r[q2]);
        }
      }
      if (lane < 16) {
#pragma unroll
        for (int q = 0; q < 16; ++q) if (q <= tr) sS[rbase + q] = r[q];
      }
    }
    __syncthreads();

    if (be < mp) {
      float invd[16];
#pragma unroll
      for (int t = 0; t < 16; ++t)
        invd[t] = 1.0f / sS[tri_i(kb + t) + kb + t];

      // phase B: row-solve, one thread per row i in [be, mp)
      {
        const int i = be + tid;
        if (i < mp) {
          const int base = tri_i(i) + kb;
          float r[16];
#pragma unroll
          for (int t = 0; t < 16; ++t) r[t] = sS[base + t];
#pragma unroll
          for (int kk = 0; kk < 15; ++kk) {
            const float c = r[kk] * invd[kk];
#pragma unroll
            for (int q = kk + 1; q < 16; ++q)
              r[q] = fmaf(-c, sS[tri_i(kb + q) + kb + kk], r[q]);
          }
#pragma unroll
          for (int t = 0; t < 16; ++t) sS[base + t] = r[t];
        }
      }
      __syncthreads();

      // phase C: trailing update. wave = row pair, lane = column chunk.
      for (int i0 = be + 2 * wid; i0 < mp; i0 += 32) {
        const int i1 = i0 + 1;
        const int rb0 = tri_i(i0) + kb;
        const int rb1 = tri_i(i1) + kb;
        float w0[16], w1[16];
#pragma unroll
        for (int t = 0; t < 16; ++t) {
          w0[t] = sS[rb0 + t] * invd[t];
          w1[t] = sS[rb1 + t] * invd[t];
        }
        const int b0 = tri_i(i0);
        const int b1 = tri_i(i1);
        for (int q0 = be; q0 <= i1; q0 += 64) {
          const int q = q0 + lane;
          const int qc = (q <= i1) ? q : i1;
          const int qb = tri_i(qc) + kb;
          float u[16];
#pragma unroll
          for (int t = 0; t < 16; ++t) u[t] = sS[qb + t];
          if (q <= i0) {
            float a = sS[b0 + q];
#pragma unroll
            for (int t = 0; t < 16; ++t) a = fmaf(-w0[t], u[t], a);
            sS[b0 + q] = a;
          }
          if (q <= i1) {
            float a = sS[b1 + q];
#pragma unroll
            for (int t = 0; t < 16; ++t) a = fmaf(-w1[t], u[t], a);
            sS[b1 + q] = a;
          }
        }
      }
      __syncthreads();
    }
  }

  // ldj partial: sum 0.5*log(d_p) over real rows
  float part = 0.0f;
  for (int p = tid; p < m; p += 1024) part += 0.5f * logf(sS[tri_i(p) + p]);
  red[tid] = part;
  __syncthreads();
  for (int s = 512; s > 0; s >>= 1) {
    if (tid < s) red[tid] += red[tid + s];
    __syncthreads();
  }
  if (tid == 0) ws[PART_OFF + blockIdx.x] = red[0];

  // LB (bf16) write: row p, cols k: [L[p][0..m-1], A0[p], A1[p], 0 pad]
  unsigned* LBg = (unsigned*)ws + lboff + d * (mp * (ks >> 1));
  const int nwords = mp * (ks >> 1);
  for (int idx = tid; idx < nwords; idx += 1024) {
    const int p = idx / (ks >> 1);
    const int k0 = (idx - p * (ks >> 1)) * 2;
    unsigned short h[2];
#pragma unroll
    for (int e = 0; e < 2; ++e) {
      const int k = k0 + e;
      float v = 0.0f;
      if (p < m) {
        if (k < m) {
          if (k <= p) {
            const float dq = sS[tri_i(k) + k];
            v = (k == p) ? sqrtf(dq) : sS[tri_i(p) + k] * rsqrtf(dq);
          }
        } else if (k == m)     v = sAmu[p * 2 + 0];
        else if (k == m + 1)   v = sAmu[p * 2 + 1];
      }
      h[e] = f2bf(v);
    }
    LBg[idx] = (unsigned)h[0] | ((unsigned)h[1] << 16);
  }
}

// ---------------------------------------------------------------------------
// Kernel B (MFMA): out[b, p] = sum_k Z'[b,k] * LB[p,k], bf16 16x16x32.
// Z' = [z_mid(0..M-1), zf, zl, 0...], LB from build. 32 rows x MP per block,
// 4 waves = 2 row-tiles x 2 p-halves. One barrier. zf/zl columns copied fp32.
// ---------------------------------------------------------------------------
template <int M, int MP, int KS, int KT, int TOFF, int OOFF, int LBOFF>
__device__ __forceinline__ void apply_impl(const float* __restrict__ z,
                                           const unsigned* __restrict__ wsu,
                                           float* __restrict__ out,
                                           char* smem, int blk)
{
  constexpr int PT = MP / 16;           // p-tiles
  constexpr int PTH = (PT + 1) / 2;     // p-tiles in first half
  constexpr int CK = KS / 8;            // 8-col chunks per Z row
  const int d   = blk & 15;
  const int bs0 = ((blk >> 4) & 63) * 32;
  const int tid = threadIdx.x;
  const int lane = tid & 63;
  const int wv   = tid >> 6;            // 4 waves
  const int rt   = wv & 1;              // row-tile (16 rows each)
  const int ph   = wv >> 1;             // p-half

  unsigned short* LBs = (unsigned short*)smem;                 // MP x KS bf16
  unsigned short* Zs  = (unsigned short*)(smem + MP * KS * 2); // 32 x KS bf16

  // stage LB: ws -> LDS, contiguous 16B chunks
  {
    const uint4* src = (const uint4*)(wsu + LBOFF + d * (MP * (KS / 2)));
    uint4* dst = (uint4*)LBs;
    for (int i = tid; i < MP * KS / 8; i += 256) dst[i] = src[i];
  }

  // stage Z' tile (bf16): row r, cols k -> z[row][TOFF+k] | zf | zl | 0
  for (int idx = tid; idx < 32 * CK; idx += 256) {
    const int r = idx / CK;
    const int k0 = (idx - r * CK) * 8;
    const float* zr = z + (size_t)((bs0 + r) * 16 + d) * 302;
    us8_t v;
    if (k0 + 8 <= M) {
#pragma unroll
      for (int t = 0; t < 4; ++t) {
        const float2 f = *(const float2*)(zr + TOFF + k0 + 2 * t);
        v[2 * t]     = f2bf(f.x);
        v[2 * t + 1] = f2bf(f.y);
      }
    } else {
#pragma unroll
      for (int e = 0; e < 8; ++e) {
        const int k = k0 + e;
        float f;
        if (k < M)          f = zr[TOFF + k];
        else if (k == M)     f = zr[0];
        else if (k == M + 1) f = zr[1];
        else                 f = 0.0f;
        v[e] = f2bf(f);
      }
    }
    *(us8_t*)&Zs[r * KS + k0] = v;
  }

  // zf / zl pass-through columns (exact fp32)
  if (tid < 64) {
    const int r = tid >> 1;
    const int which = tid & 1;
    const float* zr = z + (size_t)((bs0 + r) * 16 + d) * 302;
    out[(size_t)((bs0 + r) * 16 + d) * 306 + OOFF + (which ? (M + 1) : 0)] = zr[which];
  }
  __syncthreads();

  // A fragments: 16 rows (lane&15) x 32k per kt, register-resident
  bf8_t afr[KT];
  {
    const int row = rt * 16 + (lane & 15);
    const int koff = (lane >> 4) * 8;
#pragma unroll
    for (int kt = 0; kt < KT; ++kt)
      afr[kt] = *(const bf8_t*)&Zs[row * KS + kt * 32 + koff];
  }

  const int pt0 = ph * PTH;
  const int pt1 = (ph == 0) ? PTH : PT;
  for (int pt = pt0; pt < pt1; ++pt) {
    const int p = pt * 16 + (lane & 15);
    const unsigned short* bb = &LBs[p * KS + (lane >> 4) * 8];
    f32x4 acc = {0.0f, 0.0f, 0.0f, 0.0f};
#pragma unroll
    for (int kt = 0; kt < KT; ++kt) {
      const bf8_t bfr = *(const bf8_t*)&bb[kt * 32];
      acc = __builtin_amdgcn_mfma_f32_16x16x32_bf16(afr[kt], bfr, acc, 0, 0, 0);
    }
    if (p < M) {
      const int rbase = bs0 + rt * 16 + (lane >> 4) * 4;
#pragma unroll
      for (int e = 0; e < 4; ++e)
        out[(size_t)((rbase + e) * 16 + d) * 306 + OOFF + 1 + p] = acc[e];
    }
  }
}

__global__ __launch_bounds__(256) void apply_kernel(const float* __restrict__ z,
                                                    const unsigned* __restrict__ wsu,
                                                    float* __restrict__ out)
{
  __shared__ __attribute__((aligned(16))) char smem[64512]; // max: 160*168*2 + 32*168*2
  const int bid = blockIdx.x;
  if (bid < 1024)      apply_impl<150, 160, 168, 5, 152, 154, LB2_OFF>(z, wsu, out, smem, bid);
  else if (bid < 2048) apply_impl<100, 112, 136, 4,  52,  52, LB1_OFF>(z, wsu, out, smem, bid - 1024);
  else                 apply_impl< 50,  64,  72, 2,   2,   0, LB0_OFF>(z, wsu, out, smem, bid - 2048);
}

// ---------------------------------------------------------------------------
// Kernel C: ldj = sldj_in + sum of 48 partials
// ---------------------------------------------------------------------------
__global__ void finalize_kernel(const float* __restrict__ ws_part,
                                const float* __restrict__ sldj,
                                float* __restrict__ out, int last)
{
  if (threadIdx.x == 0) {
    float s = sldj[0];
    for (int i = 0; i < 48; ++i) s += ws_part[i];
    out[last] = s;
  }
}

extern "C" void kernel_launch(void* const* d_in, const int* in_sizes, int n_in,
                              void* d_out, int out_size, void* d_ws, size_t ws_size,
                              hipStream_t stream)
{
  const float* z       = (const float*)d_in[0];  // (16,128,16,302)
  const float* ts      = (const float*)d_in[1];  // (3,50) flat
  const float* log_tau = (const float*)d_in[2];  // (16,)
  const float* sldj    = (const float*)d_in[3];  // scalar
  float* out = (float*)d_out;                    // 16*128*16*306 + 1
  float* ws  = (float*)d_ws;

  hipLaunchKernelGGL(build_kernel, dim3(48), dim3(1024), 0, stream, ts, log_tau, ws);
  hipLaunchKernelGGL(apply_kernel, dim3(3072), dim3(256), 0, stream,
                     z, (const unsigned*)ws, out);
  hipLaunchKernelGGL(finalize_kernel, dim3(1), dim3(64), 0, stream,
                     ws + PART_OFF, sldj, out, out_size - 1);
}

// Round 6
// 190.683 us; speedup vs baseline: 1.6189x; 1.0833x over previous
//
#include <hip/hip_runtime.h>

// ws layout (32-bit word offsets). LB arrays are bf16-packed (2 per word):
// LB[j][d] has MP rows, KS bf16 columns (row stride KS), row p holds
// [ L[p][0..M-1], A_mu[p][0], A_mu[p][1], zeros... ]
#define LB0_OFF 0         // 16 * (64*72/2)   = 16*2304  = 36864
#define LB1_OFF 36864     // 16 * (112*136/2) = 16*7616  = 121856
#define LB2_OFF 158720    // 16 * (160*168/2) = 16*13440 = 215040
#define PART_OFF 373760   // 48 partial ldj sums (float)

typedef __attribute__((ext_vector_type(8))) short bf8_t;    // 8 bf16 (4 VGPR)
typedef __attribute__((ext_vector_type(8))) unsigned short us8_t;
typedef __attribute__((ext_vector_type(4))) float f32x4;

__device__ __forceinline__ int tri_i(int p) { return (p * (p + 1)) >> 1; }

__device__ __forceinline__ void tri_decode(int e, int& r, int& c) {
  r = (int)((sqrtf(8.0f * (float)e + 1.0f) - 1.0f) * 0.5f);
  if (tri_i(r + 1) <= e) ++r;
  if (tri_i(r) > e) --r;
  c = e - tri_i(r);
}

// fp32 -> bf16, round-nearest-even
__device__ __forceinline__ unsigned short f2bf(float f) {
  unsigned u = __builtin_bit_cast(unsigned, f);
  u = (u + 0x7FFFu + ((u >> 16) & 1u)) >> 16;
  return (unsigned short)u;
}

// ---------------------------------------------------------------------------
// Kernel A: per (j,d) Sigma (padded to MP, identity tail), blocked raw-Schur
// Cholesky (B=16). Phase C uses dense aligned panel buffers sU/sW (stride 20
// floats, 16B aligned -> ds_read_b128) and 4-row quads per wave so w-rows are
// amortized over all column chunks. Emits LB (bf16) + ldj partial.
// ---------------------------------------------------------------------------
__global__ __launch_bounds__(1024) void build_kernel(const float* __restrict__ ts,
                                                     const float* __restrict__ log_tau,
                                                     float* __restrict__ ws)
{
  __shared__ float sS[12880];   // packed lower triangle, padded max mp=160
  __shared__ __attribute__((aligned(16))) float sU[160 * 20]; // solved panel rows
  __shared__ __attribute__((aligned(16))) float sW[160 * 20]; // scaled panel rows
  __shared__ float stj[152];
  __shared__ float sAmu[304];
  __shared__ float sKp[304];
  __shared__ float red[1024];

  const int j = blockIdx.x >> 4;
  const int d = blockIdx.x & 15;
  const int m = (j + 1) * 50;
  const int mp    = (j == 0) ? 64      : ((j == 1) ? 112     : 160);
  const int ks    = (j == 0) ? 72      : ((j == 1) ? 136     : 168);
  const int lboff = (j == 0) ? LB0_OFF : ((j == 1) ? LB1_OFF : LB2_OFF);
  const float tpsj = (j == 0) ? 10.0f : ((j == 1) ? 20.0f : 30.0f);
  const int tid  = threadIdx.x;
  const int lane = tid & 63;
  const int wid  = tid >> 6;        // 16 waves

  const float tau = expf(log_tau[d]);
  const float cc = 1.0f / (2.0f * tau * tau);

  for (int i = tid; i < m; i += 1024) stj[i] = ts[i];
  __syncthreads();

  const float k01 = expf(-tpsj * tpsj * cc);
  const float det = 1.0f - k01 * k01;
  const float i00 = 1.0f / det;
  const float i01 = -k01 / det;

  for (int p = tid; p < m; p += 1024) {
    float tp = stj[p];
    float kp0 = expf(-tp * tp * cc);
    float dt = tp - tpsj;
    float kp1 = expf(-dt * dt * cc);
    sKp[p * 2 + 0] = kp0; sKp[p * 2 + 1] = kp1;
    sAmu[p * 2 + 0] = fmaf(kp0, i00, kp1 * i01);
    sAmu[p * 2 + 1] = fmaf(kp0, i01, kp1 * i00);
  }
  __syncthreads();

  // Sigma, padded: rows >= m are identity -> log contrib 0, L tail ignored.
  const int tot = tri_i(mp);
  for (int e = tid; e < tot; e += 1024) {
    int r, q;
    tri_decode(e, r, q);
    float v;
    if (r < m) {
      float dq = stj[r] - stj[q];
      v = expf(-dq * dq * cc)
        - fmaf(sAmu[r * 2], sKp[q * 2], sAmu[r * 2 + 1] * sKp[q * 2 + 1]);
      if (r == q) v += 1e-4f;
    } else {
      v = (r == q) ? 1.0f : 0.0f;
    }
    sS[e] = v;
  }
  __syncthreads();

  // ---- Blocked raw-Schur Cholesky, bw == 16 always ----
  const int npan = mp >> 4;
  for (int pb = 0; pb < npan; ++pb) {
    const int kb = pb << 4;
    const int be = kb + 16;

    // phase A: diag block factor. lane t (t<16) = row t in registers.
    if (wid == 0) {
      const int tr = lane & 15;
      const int rbase = tri_i(kb + tr) + kb;
      float r[16];
#pragma unroll
      for (int q = 0; q < 16; ++q) r[q] = sS[rbase + q];
#pragma unroll
      for (int kk = 0; kk < 15; ++kk) {
        const float dkk = __shfl(r[kk], kk);
        const float c = r[kk] * (-1.0f / dkk);
#pragma unroll
        for (int q2 = kk + 1; q2 < 16; ++q2) {
          const float cq2 = __shfl(r[kk], q2);
          if (tr > kk && q2 <= tr)
            r[q2] = fmaf(c, cq2, r[q2]);
        }
      }
      if (lane < 16) {
#pragma unroll
        for (int q = 0; q < 16; ++q) if (q <= tr) sS[rbase + q] = r[q];
      }
    }
    __syncthreads();

    if (be < mp) {
      float invd[16];
#pragma unroll
      for (int t = 0; t < 16; ++t)
        invd[t] = 1.0f / sS[tri_i(kb + t) + kb + t];

      // phase B: row-solve, one thread per row i in [be, mp); write solved
      // row (u) and scaled row (w) into dense aligned buffers for phase C.
      {
        const int i = be + tid;
        if (i < mp) {
          const int base = tri_i(i) + kb;
          float r[16];
#pragma unroll
          for (int t = 0; t < 16; ++t) r[t] = sS[base + t];
#pragma unroll
          for (int kk = 0; kk < 15; ++kk) {
            const float c = r[kk] * invd[kk];
#pragma unroll
            for (int q = kk + 1; q < 16; ++q)
              r[q] = fmaf(-c, sS[tri_i(kb + q) + kb + kk], r[q]);
          }
#pragma unroll
          for (int t = 0; t < 16; ++t) sS[base + t] = r[t];
          float w[16];
#pragma unroll
          for (int t = 0; t < 16; ++t) w[t] = r[t] * invd[t];
          float4* up = (float4*)&sU[i * 20];
          float4* wp = (float4*)&sW[i * 20];
#pragma unroll
          for (int c4 = 0; c4 < 4; ++c4) {
            up[c4] = *(float4*)&r[c4 * 4];
            wp[c4] = *(float4*)&w[c4 * 4];
          }
        }
      }
      __syncthreads();

      // phase C: trailing update. wave = 4-row quad, lane = col (stride 64).
      for (int i0 = be + 4 * wid; i0 < mp; i0 += 64) {
        float wreg[4][16];
        int rb[4];
#pragma unroll
        for (int r = 0; r < 4; ++r) {
          const float4* wp = (const float4*)&sW[(i0 + r) * 20];
#pragma unroll
          for (int c4 = 0; c4 < 4; ++c4)
            *(float4*)&wreg[r][c4 * 4] = wp[c4];
          rb[r] = tri_i(i0 + r);
        }
        for (int q0 = be; q0 <= i0 + 3; q0 += 64) {
          const int q = q0 + lane;
          const int qc = (q <= i0 + 3) ? q : (i0 + 3);
          const float4* up = (const float4*)&sU[qc * 20];
          float u[16];
#pragma unroll
          for (int c4 = 0; c4 < 4; ++c4) *(float4*)&u[c4 * 4] = up[c4];
#pragma unroll
          for (int r = 0; r < 4; ++r) {
            if (q <= i0 + r) {
              const int a = rb[r] + q;
              float acc = sS[a];
#pragma unroll
              for (int t = 0; t < 16; ++t) acc = fmaf(-wreg[r][t], u[t], acc);
              sS[a] = acc;
            }
          }
        }
      }
      __syncthreads();
    }
  }

  // ldj partial: sum 0.5*log(d_p) over real rows
  float part = 0.0f;
  for (int p = tid; p < m; p += 1024) part += 0.5f * logf(sS[tri_i(p) + p]);
  red[tid] = part;
  __syncthreads();
  for (int s = 512; s > 0; s >>= 1) {
    if (tid < s) red[tid] += red[tid + s];
    __syncthreads();
  }
  if (tid == 0) ws[PART_OFF + blockIdx.x] = red[0];

  // LB (bf16) write: row p, cols k: [L[p][0..m-1], A0[p], A1[p], 0 pad]
  unsigned* LBg = (unsigned*)ws + lboff + d * (mp * (ks >> 1));
  const int nwords = mp * (ks >> 1);
  for (int idx = tid; idx < nwords; idx += 1024) {
    const int p = idx / (ks >> 1);
    const int k0 = (idx - p * (ks >> 1)) * 2;
    unsigned short h[2];
#pragma unroll
    for (int e = 0; e < 2; ++e) {
      const int k = k0 + e;
      float v = 0.0f;
      if (p < m) {
        if (k < m) {
          if (k <= p) {
            const float dq = sS[tri_i(k) + k];
            v = (k == p) ? sqrtf(dq) : sS[tri_i(p) + k] * rsqrtf(dq);
          }
        } else if (k == m)     v = sAmu[p * 2 + 0];
        else if (k == m + 1)   v = sAmu[p * 2 + 1];
      }
      h[e] = f2bf(v);
    }
    LBg[idx] = (unsigned)h[0] | ((unsigned)h[1] << 16);
  }
}

// ---------------------------------------------------------------------------
// Kernel B (MFMA): out[b, p] = sum_k Z'[b,k] * LB[p,k], bf16 16x16x32.
// Z' tile staged in LDS (~11 KB); B-fragments load DIRECTLY from global ws
// (L2-resident, 16B-aligned rows) -> no LB staging, high occupancy.
// ---------------------------------------------------------------------------
template <int M, int MP, int KS, int KT, int TOFF, int OOFF, int LBOFF>
__device__ __forceinline__ void apply_impl(const float* __restrict__ z,
                                           const unsigned* __restrict__ wsu,
                                           float* __restrict__ out,
                                           char* smem, int blk)
{
  constexpr int PT = MP / 16;           // p-tiles
  constexpr int PTH = (PT + 1) / 2;     // p-tiles in first half
  constexpr int CK = KS / 8;            // 8-col chunks per Z row
  const int d   = blk & 15;
  const int bs0 = ((blk >> 4) & 63) * 32;
  const int tid = threadIdx.x;
  const int lane = tid & 63;
  const int wv   = tid >> 6;            // 4 waves
  const int rt   = wv & 1;              // row-tile (16 rows each)
  const int ph   = wv >> 1;             // p-half

  unsigned short* Zs = (unsigned short*)smem;   // 32 x KS bf16

  // stage Z' tile (bf16): row r, cols k -> z[row][TOFF+k] | zf | zl | 0
  for (int idx = tid; idx < 32 * CK; idx += 256) {
    const int r = idx / CK;
    const int k0 = (idx - r * CK) * 8;
    const float* zr = z + (size_t)((bs0 + r) * 16 + d) * 302;
    us8_t v;
    if (k0 + 8 <= M) {
#pragma unroll
      for (int t = 0; t < 4; ++t) {
        const float2 f = *(const float2*)(zr + TOFF + k0 + 2 * t);
        v[2 * t]     = f2bf(f.x);
        v[2 * t + 1] = f2bf(f.y);
      }
    } else {
#pragma unroll
      for (int e = 0; e < 8; ++e) {
        const int k = k0 + e;
        float f;
        if (k < M)           f = zr[TOFF + k];
        else if (k == M)     f = zr[0];
        else if (k == M + 1) f = zr[1];
        else                 f = 0.0f;
        v[e] = f2bf(f);
      }
    }
    *(us8_t*)&Zs[r * KS + k0] = v;
  }

  // zf / zl pass-through columns (exact fp32)
  if (tid < 64) {
    const int r = tid >> 1;
    const int which = tid & 1;
    const float* zr = z + (size_t)((bs0 + r) * 16 + d) * 302;
    out[(size_t)((bs0 + r) * 16 + d) * 306 + OOFF + (which ? (M + 1) : 0)] = zr[which];
  }
  __syncthreads();

  // A fragments: 16 rows (lane&15) x 32k per kt, register-resident
  bf8_t afr[KT];
  {
    const int row = rt * 16 + (lane & 15);
    const int koff = (lane >> 4) * 8;
#pragma unroll
    for (int kt = 0; kt < KT; ++kt)
      afr[kt] = *(const bf8_t*)&Zs[row * KS + kt * 32 + koff];
  }

  const unsigned short* LBd = (const unsigned short*)(wsu + LBOFF + d * (MP * (KS / 2)));
  const int pt0 = ph * PTH;
  const int pt1 = (ph == 0) ? PTH : PT;
  for (int pt = pt0; pt < pt1; ++pt) {
    const int p = pt * 16 + (lane & 15);
    const unsigned short* bb = &LBd[p * KS + (lane >> 4) * 8];
    f32x4 acc = {0.0f, 0.0f, 0.0f, 0.0f};
#pragma unroll
    for (int kt = 0; kt < KT; ++kt) {
      const bf8_t bfr = *(const bf8_t*)&bb[kt * 32];   // 16B global load (L2)
      acc = __builtin_amdgcn_mfma_f32_16x16x32_bf16(afr[kt], bfr, acc, 0, 0, 0);
    }
    if (p < M) {
      const int rbase = bs0 + rt * 16 + (lane >> 4) * 4;
#pragma unroll
      for (int e = 0; e < 4; ++e)
        out[(size_t)((rbase + e) * 16 + d) * 306 + OOFF + 1 + p] = acc[e];
    }
  }
}

__global__ __launch_bounds__(256) void apply_kernel(const float* __restrict__ z,
                                                    const unsigned* __restrict__ wsu,
                                                    float* __restrict__ out)
{
  __shared__ __attribute__((aligned(16))) char smem[10752]; // 32*168*2
  const int bid = blockIdx.x;
  if (bid < 1024)      apply_impl<150, 160, 168, 5, 152, 154, LB2_OFF>(z, wsu, out, smem, bid);
  else if (bid < 2048) apply_impl<100, 112, 136, 4,  52,  52, LB1_OFF>(z, wsu, out, smem, bid - 1024);
  else                 apply_impl< 50,  64,  72, 2,   2,   0, LB0_OFF>(z, wsu, out, smem, bid - 2048);
}

// ---------------------------------------------------------------------------
// Kernel C: ldj = sldj_in + sum of 48 partials
// ---------------------------------------------------------------------------
__global__ void finalize_kernel(const float* __restrict__ ws_part,
                                const float* __restrict__ sldj,
                                float* __restrict__ out, int last)
{
  if (threadIdx.x == 0) {
    float s = sldj[0];
    for (int i = 0; i < 48; ++i) s += ws_part[i];
    out[last] = s;
  }
}

extern "C" void kernel_launch(void* const* d_in, const int* in_sizes, int n_in,
                              void* d_out, int out_size, void* d_ws, size_t ws_size,
                              hipStream_t stream)
{
  const float* z       = (const float*)d_in[0];  // (16,128,16,302)
  const float* ts      = (const float*)d_in[1];  // (3,50) flat
  const float* log_tau = (const float*)d_in[2];  // (16,)
  const float* sldj    = (const float*)d_in[3];  // scalar
  float* out = (float*)d_out;                    // 16*128*16*306 + 1
  float* ws  = (float*)d_ws;

  hipLaunchKernelGGL(build_kernel, dim3(48), dim3(1024), 0, stream, ts, log_tau, ws);
  hipLaunchKernelGGL(apply_kernel, dim3(3072), dim3(256), 0, stream,
                     z, (const unsigned*)ws, out);
  hipLaunchKernelGGL(finalize_kernel, dim3(1), dim3(64), 0, stream,
                     ws + PART_OFF, sldj, out, out_size - 1);
}